// Round 8
// baseline (203.427 us; speedup 1.0000x reference)
//
#include <hip/hip_runtime.h>

typedef _Float16 half8 __attribute__((ext_vector_type(8)));
typedef float f32x4 __attribute__((ext_vector_type(4)));

union Frag { half8 v; unsigned int u32[4]; uint4 u4; };
union Pack4 { _Float16 h[4]; uint2 u; };

constexpr int S = 4096;
constexpr int D = 64;
constexpr int NB = 16;
constexpr int LTS = 72;   // f16 LDS row stride (dword stride 36): min-phase b128 frag reads + b64 P writes

// ---- fused prepass: K f32 -> f16 row-major; V f32 -> f16 transposed [b][d][s] ----
__global__ __launch_bounds__(256)
void prep_kernel(const float* __restrict__ K, const float* __restrict__ V,
                 _Float16* __restrict__ K16, _Float16* __restrict__ VT) {
    __shared__ float tl[64 * 66];
    const int tid = threadIdx.x;
    const int s0 = blockIdx.x * 64;
    const int b  = blockIdx.y;
    const float* Kb = K + ((size_t)b * S + s0) * D;
    const float* Vb = V + ((size_t)b * S + s0) * D;
    _Float16* K16b = K16 + ((size_t)b * S + s0) * D;

    #pragma unroll
    for (int i = 0; i < 2; ++i) {
        int e8 = tid + 256 * i;
        float4 a = ((const float4*)Kb)[2 * e8];
        float4 c = ((const float4*)Kb)[2 * e8 + 1];
        Frag f;
        f.v[0]=(_Float16)a.x; f.v[1]=(_Float16)a.y; f.v[2]=(_Float16)a.z; f.v[3]=(_Float16)a.w;
        f.v[4]=(_Float16)c.x; f.v[5]=(_Float16)c.y; f.v[6]=(_Float16)c.z; f.v[7]=(_Float16)c.w;
        ((uint4*)K16b)[e8] = f.u4;
    }
    #pragma unroll
    for (int i = 0; i < 4; ++i) {
        int fi = tid + 256 * i;
        int r = fi >> 4, c4 = (fi & 15) << 2;
        float4 v = *(const float4*)(Vb + (size_t)r * D + c4);
        float2* p = (float2*)&tl[r * 66 + c4];
        p[0] = make_float2(v.x, v.y);
        p[1] = make_float2(v.z, v.w);
    }
    __syncthreads();
    _Float16* VTb = VT + (size_t)b * D * S;
    #pragma unroll
    for (int i = 0; i < 2; ++i) {
        int fi = tid + 256 * i;
        int d = fi >> 3, s8 = (fi & 7) << 3;
        Frag f;
        #pragma unroll
        for (int j = 0; j < 8; ++j) f.v[j] = (_Float16)tl[(s8 + j) * 66 + d];
        *(uint4*)(VTb + (size_t)d * S + s0 + s8) = f.u4;
    }
}

// ============ hot loop: 32 q-rows/wave (2 q-groups), 128 q-rows/block ============
// S^T = K @ Q^T operand swap; each kf/vf frag read feeds 2 MFMAs (m-block x2).
// SPLIT=1: unnormalized O-partial + l-partial to workspace. SPLIT=0: direct Out.
template <int SPLIT>
__device__ __forceinline__
void fattn_body(const float* __restrict__ Q, const _Float16* __restrict__ K16,
                const _Float16* __restrict__ VT16, float* __restrict__ Out,
                float* __restrict__ OP, float* __restrict__ LP,
                int b, int J, int t0, int t1, int h) {
    __shared__ __align__(16) _Float16 kt[64 * LTS];        // 9.2 KB  K tile [key][d]
    __shared__ __align__(16) _Float16 vt[64 * LTS];        // 9.2 KB  V^T tile [d][key]
    __shared__ __align__(16) _Float16 pt[4 * 32 * LTS];    // 18.4 KB per-wave P [q 32][key 64]

    const int tid  = threadIdx.x;
    const int wave = tid >> 6;
    const int lane = tid & 63;
    const int ln   = lane & 15;
    const int quad = lane >> 4;

    const float* Qb = Q + (size_t)b * S * D;
    const _Float16* Kb = K16 + (size_t)b * S * D;
    const _Float16* VTb = VT16 + (size_t)b * D * S;

    const float qscale = 0.125f * 1.44269504088896340736f;  // 1/sqrt(64) * log2(e)
    const int qrow_base = J * 128 + wave * 32;
    const int tw = (qrow_base + 31) >> 6;     // wave's diagonal tile; t>tw fully masked (exp->0)

    // Q fragments qf[qg][ks]: MFMA *B* operand (n=q=ln, k=d=quad*8+j)
    Frag qf[2][2];
    #pragma unroll
    for (int qg = 0; qg < 2; ++qg) {
        const float* qrow = Qb + (size_t)(qrow_base + qg * 16 + ln) * D + quad * 8;
        #pragma unroll
        for (int ks = 0; ks < 2; ++ks) {
            float4 a = *(const float4*)(qrow + ks * 32);
            float4 c = *(const float4*)(qrow + ks * 32 + 4);
            Frag f;
            f.v[0]=(_Float16)(a.x*qscale); f.v[1]=(_Float16)(a.y*qscale);
            f.v[2]=(_Float16)(a.z*qscale); f.v[3]=(_Float16)(a.w*qscale);
            f.v[4]=(_Float16)(c.x*qscale); f.v[5]=(_Float16)(c.y*qscale);
            f.v[6]=(_Float16)(c.z*qscale); f.v[7]=(_Float16)(c.w*qscale);
            qf[qg][ks] = f;
        }
    }

    f32x4 o[2][4] = {};
    float l_acc[2] = {0.f, 0.f};
    _Float16* ptw = pt + wave * 32 * LTS;

    for (int t = t0; t < t1; ++t) {
        const int k0 = t * 64;
        __syncthreads();

        #pragma unroll
        for (int i = 0; i < 2; ++i) {
            int fi = tid + 256 * i;
            int r = fi >> 3, c8 = (fi & 7) << 3;
            uint4 kk = *(const uint4*)(Kb + (size_t)(k0 + r) * D + c8);
            uint4 vv = *(const uint4*)(VTb + (size_t)r * S + k0 + c8);
            *(uint4*)(kt + r * LTS + c8) = kk;
            *(uint4*)(vt + r * LTS + c8) = vv;
        }
        __syncthreads();

        // ---- S^T = K @ Q^T, per 16-key group; kf reused across both q-groups ----
        #pragma unroll
        for (int ct = 0; ct < 4; ++ct) {
            Frag kf0, kf1;
            kf0.u4 = *(const uint4*)(kt + (ct * 16 + ln) * LTS + quad * 8);
            kf1.u4 = *(const uint4*)(kt + (ct * 16 + ln) * LTS + 32 + quad * 8);
            #pragma unroll
            for (int qg = 0; qg < 2; ++qg) {
                f32x4 acc = {0.f, 0.f, 0.f, 0.f};
                acc = __builtin_amdgcn_mfma_f32_16x16x32_f16(kf0.v, qf[qg][0].v, acc, 0, 0, 0);
                acc = __builtin_amdgcn_mfma_f32_16x16x32_f16(kf1.v, qf[qg][1].v, acc, 0, 0, 0);
                if (t >= tw) {   // diagonal (partial) or beyond (fully masked -> exp=0)
                    int keyb = k0 + ct * 16 + quad * 4;
                    int qrow = qrow_base + qg * 16 + ln;
                    #pragma unroll
                    for (int r = 0; r < 4; ++r)
                        if (keyb + r > qrow) acc[r] = -1e30f;
                }
                Pack4 pk;
                float psum = 0.f;
                #pragma unroll
                for (int r = 0; r < 4; ++r) {
                    float p = exp2f(acc[r]);   // no-max softmax: exact by shift-invariance
                    psum += p;
                    pk.h[r] = (_Float16)p;
                }
                l_acc[qg] += psum;
                *(uint2*)(ptw + (qg * 16 + ln) * LTS + ct * 16 + quad * 4) = pk.u;
            }
        }

        // ---- P A-frags (m=q, k=key); same-wave RAW, no barrier ----
        Frag pf[2][2];
        #pragma unroll
        for (int qg = 0; qg < 2; ++qg)
            #pragma unroll
            for (int ks = 0; ks < 2; ++ks)
                pf[qg][ks].u4 = *(const uint4*)(ptw + (qg * 16 + ln) * LTS + ks * 32 + quad * 8);

        // ---- O += P @ V; vf reused across both q-groups ----
        #pragma unroll
        for (int ks = 0; ks < 2; ++ks) {
            #pragma unroll
            for (int sub = 0; sub < 4; ++sub) {
                Frag vf;
                vf.u4 = *(const uint4*)(vt + (sub * 16 + ln) * LTS + ks * 32 + quad * 8);
                #pragma unroll
                for (int qg = 0; qg < 2; ++qg)
                    o[qg][sub] = __builtin_amdgcn_mfma_f32_16x16x32_f16(pf[qg][ks].v, vf.v, o[qg][sub], 0, 0, 0);
            }
        }
    }

    // full denom per q (sum 4 quad-partials); lane ln holds denom of q = qg*16+ln
    float lf[2];
    #pragma unroll
    for (int qg = 0; qg < 2; ++qg) {
        float x = l_acc[qg];
        x += __shfl_xor(x, 16, 64);
        x += __shfl_xor(x, 32, 64);
        lf[qg] = x;
    }

    if (SPLIT) {
        float* OPb = OP + (size_t)((b * 32 + J) * 2 + h) * 128 * 64;
        float* LPb = LP + (size_t)((b * 32 + J) * 2 + h) * 128;
        #pragma unroll
        for (int qg = 0; qg < 2; ++qg) {
            #pragma unroll
            for (int r = 0; r < 4; ++r)
                #pragma unroll
                for (int sub = 0; sub < 4; ++sub)
                    OPb[(wave * 32 + qg * 16 + quad * 4 + r) * 64 + sub * 16 + ln] = o[qg][sub][r];
            if (quad == 0) LPb[wave * 32 + qg * 16 + ln] = lf[qg];
        }
    } else {
        float* Ob = Out + (size_t)b * S * D;
        #pragma unroll
        for (int qg = 0; qg < 2; ++qg) {
            #pragma unroll
            for (int r = 0; r < 4; ++r) {
                float lrow = __shfl(lf[qg], quad * 4 + r, 64);
                float inv = 1.0f / lrow;
                #pragma unroll
                for (int sub = 0; sub < 4; ++sub)
                    Ob[(size_t)(qrow_base + qg * 16 + quad * 4 + r) * D + sub * 16 + ln] =
                        o[qg][sub][r] * inv;
            }
        }
    }
}

// split-K x2 over 128-q-row blocks: grid 1024 = 32 J x 2 halves x 16 batches, LPT
__global__ __launch_bounds__(256, 4)
void fattn_split_kernel(const float* __restrict__ Q, const _Float16* __restrict__ K16,
                        const _Float16* __restrict__ VT16,
                        float* __restrict__ OP, float* __restrict__ LP) {
    const int bx = blockIdx.x;
    const int J = 31 - (bx >> 5);
    const int h = (bx >> 4) & 1;
    const int b = bx & 15;
    const int n  = 2 * J + 2;
    const int n0 = (n + 1) >> 1;          // = J+1
    const int t0 = h ? n0 : 0;
    const int t1 = h ? n  : n0;
    fattn_body<1>(Q, K16, VT16, nullptr, OP, LP, b, J, t0, t1, h);
}

// fallback (ws too small): full range, direct store
__global__ __launch_bounds__(256, 4)
void fattn_kernel(const float* __restrict__ Q, const _Float16* __restrict__ K16,
                  const _Float16* __restrict__ VT16, float* __restrict__ Out) {
    const int bx = blockIdx.x;
    const int J = 31 - (bx >> 4);
    const int b = bx & 15;
    fattn_body<0>(Q, K16, VT16, Out, nullptr, nullptr, b, J, 0, 2 * J + 2, 0);
}

// merge: Out = (P0 + P1) / (l0 + l1); one block per (b, J) tile of 128 rows
__global__ __launch_bounds__(256)
void reduce_kernel(const float* __restrict__ OP, const float* __restrict__ LP,
                   float* __restrict__ Out) {
    const int rb = blockIdx.x;
    const int b  = rb & 15;
    const int J  = rb >> 4;
    const int tid = threadIdx.x;
    const float* p0 = OP + (size_t)((b * 32 + J) * 2) * 8192;
    const float* p1 = p0 + 8192;
    const float* l0 = LP + (size_t)((b * 32 + J) * 2) * 128;
    const float* l1 = l0 + 128;
    float* Ob = Out + (size_t)b * S * D + (size_t)J * 8192;
    #pragma unroll
    for (int i = 0; i < 8; ++i) {
        int e4 = tid + 256 * i;                 // float4 index within 8192 floats
        float4 a = ((const float4*)p0)[e4];
        float4 c = ((const float4*)p1)[e4];
        int q = e4 >> 4;
        float inv = 1.0f / (l0[q] + l1[q]);
        float4 r;
        r.x = (a.x + c.x) * inv;
        r.y = (a.y + c.y) * inv;
        r.z = (a.z + c.z) * inv;
        r.w = (a.w + c.w) * inv;
        ((float4*)Ob)[e4] = r;
    }
}

extern "C" void kernel_launch(void* const* d_in, const int* in_sizes, int n_in,
                              void* d_out, int out_size, void* d_ws, size_t ws_size,
                              hipStream_t stream) {
    const float* Q = (const float*)d_in[0];
    const float* K = (const float*)d_in[1];
    const float* V = (const float*)d_in[2];
    float* O = (float*)d_out;

    const size_t prepBytes = (size_t)NB * S * D * 2;        // 8.39 MB each
    _Float16* K16  = (_Float16*)d_ws;
    _Float16* VT16 = (_Float16*)((char*)d_ws + prepBytes);

    const size_t opOff = 2 * prepBytes;                     // 16.78 MB
    const size_t opBytes = (size_t)NB * 32 * 2 * 128 * 64 * 4;  // 33.55 MB
    const size_t lpOff = opOff + opBytes;
    const size_t lpBytes = (size_t)NB * 32 * 2 * 128 * 4;   // 0.52 MB
    const size_t need = lpOff + lpBytes;                    // ~50.9 MB (same as R7: known fit)

    hipLaunchKernelGGL(prep_kernel, dim3(S / 64, NB), dim3(256), 0, stream, K, V, K16, VT16);

    if (ws_size >= need) {
        float* OP = (float*)((char*)d_ws + opOff);
        float* LP = (float*)((char*)d_ws + lpOff);
        hipLaunchKernelGGL(fattn_split_kernel, dim3(64 * NB), dim3(256), 0, stream,
                           Q, K16, VT16, OP, LP);
        hipLaunchKernelGGL(reduce_kernel, dim3(32 * NB), dim3(256), 0, stream, OP, LP, O);
    } else {
        hipLaunchKernelGGL(fattn_kernel, dim3(32 * NB), dim3(256), 0, stream, Q, K16, VT16, O);
    }
}

// Round 9
// 200.261 us; speedup vs baseline: 1.0158x; 1.0158x over previous
//
#include <hip/hip_runtime.h>

typedef _Float16 half8 __attribute__((ext_vector_type(8)));
typedef float f32x4 __attribute__((ext_vector_type(4)));

union Frag { half8 v; unsigned int u32[4]; uint4 u4; };
union Pack4 { _Float16 h[4]; uint2 u; };

constexpr int S = 4096;
constexpr int D = 64;
constexpr int NB = 16;
constexpr int LTS = 72;   // f16 LDS row stride (dword stride 36): min-phase b128 frag reads + b64 P writes

// ---- fused prepass: K f32 -> f16 row-major; V f32 -> f16 transposed [b][d][s] ----
__global__ __launch_bounds__(256)
void prep_kernel(const float* __restrict__ K, const float* __restrict__ V,
                 _Float16* __restrict__ K16, _Float16* __restrict__ VT) {
    __shared__ float tl[64 * 66];
    const int tid = threadIdx.x;
    const int s0 = blockIdx.x * 64;
    const int b  = blockIdx.y;
    const float* Kb = K + ((size_t)b * S + s0) * D;
    const float* Vb = V + ((size_t)b * S + s0) * D;
    _Float16* K16b = K16 + ((size_t)b * S + s0) * D;

    #pragma unroll
    for (int i = 0; i < 2; ++i) {
        int e8 = tid + 256 * i;
        float4 a = ((const float4*)Kb)[2 * e8];
        float4 c = ((const float4*)Kb)[2 * e8 + 1];
        Frag f;
        f.v[0]=(_Float16)a.x; f.v[1]=(_Float16)a.y; f.v[2]=(_Float16)a.z; f.v[3]=(_Float16)a.w;
        f.v[4]=(_Float16)c.x; f.v[5]=(_Float16)c.y; f.v[6]=(_Float16)c.z; f.v[7]=(_Float16)c.w;
        ((uint4*)K16b)[e8] = f.u4;
    }
    #pragma unroll
    for (int i = 0; i < 4; ++i) {
        int fi = tid + 256 * i;
        int r = fi >> 4, c4 = (fi & 15) << 2;
        float4 v = *(const float4*)(Vb + (size_t)r * D + c4);
        float2* p = (float2*)&tl[r * 66 + c4];
        p[0] = make_float2(v.x, v.y);
        p[1] = make_float2(v.z, v.w);
    }
    __syncthreads();
    _Float16* VTb = VT + (size_t)b * D * S;
    #pragma unroll
    for (int i = 0; i < 2; ++i) {
        int fi = tid + 256 * i;
        int d = fi >> 3, s8 = (fi & 7) << 3;
        Frag f;
        #pragma unroll
        for (int j = 0; j < 8; ++j) f.v[j] = (_Float16)tl[(s8 + j) * 66 + d];
        *(uint4*)(VTb + (size_t)d * S + s0 + s8) = f.u4;
    }
}

// ============ hot loop: 32 q-rows/wave (2 q-groups), 128 q-rows/block ============
// S^T = K @ Q^T operand swap; each kf/vf frag read feeds 2 MFMAs (m-block x2).
// SPLIT=1: normalized f16 O-partial (O/l) + l to workspace. SPLIT=0: direct Out.
template <int SPLIT>
__device__ __forceinline__
void fattn_body(const float* __restrict__ Q, const _Float16* __restrict__ K16,
                const _Float16* __restrict__ VT16, float* __restrict__ Out,
                _Float16* __restrict__ OP, float* __restrict__ LP,
                int b, int J, int t0, int t1, int h) {
    __shared__ __align__(16) _Float16 kt[64 * LTS];        // 9.2 KB  K tile [key][d]
    __shared__ __align__(16) _Float16 vt[64 * LTS];        // 9.2 KB  V^T tile [d][key]
    __shared__ __align__(16) _Float16 pt[4 * 32 * LTS];    // 18.4 KB per-wave P [q 32][key 64]

    const int tid  = threadIdx.x;
    const int wave = tid >> 6;
    const int lane = tid & 63;
    const int ln   = lane & 15;
    const int quad = lane >> 4;

    const float* Qb = Q + (size_t)b * S * D;
    const _Float16* Kb = K16 + (size_t)b * S * D;
    const _Float16* VTb = VT16 + (size_t)b * D * S;

    const float qscale = 0.125f * 1.44269504088896340736f;  // 1/sqrt(64) * log2(e)
    const int qrow_base = J * 128 + wave * 32;
    const int tw = (qrow_base + 31) >> 6;     // wave's diagonal tile; t>tw fully masked (exp->0)

    // Q fragments qf[qg][ks]: MFMA *B* operand (n=q=ln, k=d=quad*8+j)
    Frag qf[2][2];
    #pragma unroll
    for (int qg = 0; qg < 2; ++qg) {
        const float* qrow = Qb + (size_t)(qrow_base + qg * 16 + ln) * D + quad * 8;
        #pragma unroll
        for (int ks = 0; ks < 2; ++ks) {
            float4 a = *(const float4*)(qrow + ks * 32);
            float4 c = *(const float4*)(qrow + ks * 32 + 4);
            Frag f;
            f.v[0]=(_Float16)(a.x*qscale); f.v[1]=(_Float16)(a.y*qscale);
            f.v[2]=(_Float16)(a.z*qscale); f.v[3]=(_Float16)(a.w*qscale);
            f.v[4]=(_Float16)(c.x*qscale); f.v[5]=(_Float16)(c.y*qscale);
            f.v[6]=(_Float16)(c.z*qscale); f.v[7]=(_Float16)(c.w*qscale);
            qf[qg][ks] = f;
        }
    }

    f32x4 o[2][4] = {};
    float l_acc[2] = {0.f, 0.f};
    _Float16* ptw = pt + wave * 32 * LTS;

    for (int t = t0; t < t1; ++t) {
        const int k0 = t * 64;
        __syncthreads();

        #pragma unroll
        for (int i = 0; i < 2; ++i) {
            int fi = tid + 256 * i;
            int r = fi >> 3, c8 = (fi & 7) << 3;
            uint4 kk = *(const uint4*)(Kb + (size_t)(k0 + r) * D + c8);
            uint4 vv = *(const uint4*)(VTb + (size_t)r * S + k0 + c8);
            *(uint4*)(kt + r * LTS + c8) = kk;
            *(uint4*)(vt + r * LTS + c8) = vv;
        }
        __syncthreads();

        // ---- S^T = K @ Q^T, per 16-key group; kf reused across both q-groups ----
        #pragma unroll
        for (int ct = 0; ct < 4; ++ct) {
            Frag kf0, kf1;
            kf0.u4 = *(const uint4*)(kt + (ct * 16 + ln) * LTS + quad * 8);
            kf1.u4 = *(const uint4*)(kt + (ct * 16 + ln) * LTS + 32 + quad * 8);
            #pragma unroll
            for (int qg = 0; qg < 2; ++qg) {
                f32x4 acc = {0.f, 0.f, 0.f, 0.f};
                acc = __builtin_amdgcn_mfma_f32_16x16x32_f16(kf0.v, qf[qg][0].v, acc, 0, 0, 0);
                acc = __builtin_amdgcn_mfma_f32_16x16x32_f16(kf1.v, qf[qg][1].v, acc, 0, 0, 0);
                if (t >= tw) {   // diagonal (partial) or beyond (fully masked -> exp=0)
                    int keyb = k0 + ct * 16 + quad * 4;
                    int qrow = qrow_base + qg * 16 + ln;
                    #pragma unroll
                    for (int r = 0; r < 4; ++r)
                        if (keyb + r > qrow) acc[r] = -1e30f;
                }
                Pack4 pk;
                float psum = 0.f;
                #pragma unroll
                for (int r = 0; r < 4; ++r) {
                    float p = exp2f(acc[r]);   // no-max softmax: exact by shift-invariance
                    psum += p;
                    pk.h[r] = (_Float16)p;
                }
                l_acc[qg] += psum;
                *(uint2*)(ptw + (qg * 16 + ln) * LTS + ct * 16 + quad * 4) = pk.u;
            }
        }

        // ---- P A-frags (m=q, k=key); same-wave RAW, no barrier ----
        Frag pf[2][2];
        #pragma unroll
        for (int qg = 0; qg < 2; ++qg)
            #pragma unroll
            for (int ks = 0; ks < 2; ++ks)
                pf[qg][ks].u4 = *(const uint4*)(ptw + (qg * 16 + ln) * LTS + ks * 32 + quad * 8);

        // ---- O += P @ V; vf reused across both q-groups ----
        #pragma unroll
        for (int ks = 0; ks < 2; ++ks) {
            #pragma unroll
            for (int sub = 0; sub < 4; ++sub) {
                Frag vf;
                vf.u4 = *(const uint4*)(vt + (sub * 16 + ln) * LTS + ks * 32 + quad * 8);
                #pragma unroll
                for (int qg = 0; qg < 2; ++qg)
                    o[qg][sub] = __builtin_amdgcn_mfma_f32_16x16x32_f16(pf[qg][ks].v, vf.v, o[qg][sub], 0, 0, 0);
            }
        }
    }

    // full denom per q (sum 4 quad-partials); lane ln holds denom of q = qg*16+ln
    float lf[2];
    #pragma unroll
    for (int qg = 0; qg < 2; ++qg) {
        float x = l_acc[qg];
        x += __shfl_xor(x, 16, 64);
        x += __shfl_xor(x, 32, 64);
        lf[qg] = x;
    }

    if (SPLIT) {
        // normalized f16 partial: Ohat = O/l (|Ohat| <= max|v|, f16-safe); merge = sum(l*Ohat)/sum(l)
        _Float16* OPb = OP + (size_t)(((b * 32 + J) * 4 + h)) * 8192;
        float* LPb = LP + (size_t)(((b * 32 + J) * 4 + h)) * 128;
        #pragma unroll
        for (int qg = 0; qg < 2; ++qg) {
            if (quad == 0) LPb[wave * 32 + qg * 16 + ln] = lf[qg];
            #pragma unroll
            for (int r = 0; r < 4; ++r) {
                float lrow = __shfl(lf[qg], quad * 4 + r, 64);
                float inv = (lrow > 0.f) ? (1.0f / lrow) : 0.f;  // guard: fully-masked/empty chunk
                #pragma unroll
                for (int sub = 0; sub < 4; ++sub)
                    OPb[(wave * 32 + qg * 16 + quad * 4 + r) * 64 + sub * 16 + ln] =
                        (_Float16)(o[qg][sub][r] * inv);
            }
        }
    } else {
        float* Ob = Out + (size_t)b * S * D;
        #pragma unroll
        for (int qg = 0; qg < 2; ++qg) {
            #pragma unroll
            for (int r = 0; r < 4; ++r) {
                float lrow = __shfl(lf[qg], quad * 4 + r, 64);
                float inv = 1.0f / lrow;
                #pragma unroll
                for (int sub = 0; sub < 4; ++sub)
                    Ob[(size_t)(qrow_base + qg * 16 + quad * 4 + r) * D + sub * 16 + ln] =
                        o[qg][sub][r] * inv;
            }
        }
    }
}

// split-K x4 over 128-q-row blocks: grid 2048 = 32 J x 4 quarters x 16 batches, LPT.
// 8 blocks dispatched per CU over 4 resident slots -> backfill queue (R7 mechanism).
__global__ __launch_bounds__(256, 4)
void fattn_split_kernel(const float* __restrict__ Q, const _Float16* __restrict__ K16,
                        const _Float16* __restrict__ VT16,
                        _Float16* __restrict__ OP, float* __restrict__ LP) {
    const int bx = blockIdx.x;
    const int J = 31 - (bx >> 6);
    const int h = (bx >> 4) & 3;
    const int b = bx & 15;
    const int n  = 2 * J + 2;
    const int t0 = (h * n) >> 2;
    const int t1 = ((h + 1) * n) >> 2;
    fattn_body<1>(Q, K16, VT16, nullptr, OP, LP, b, J, t0, t1, h);
}

// fallback (ws too small): full range, direct store
__global__ __launch_bounds__(256, 4)
void fattn_kernel(const float* __restrict__ Q, const _Float16* __restrict__ K16,
                  const _Float16* __restrict__ VT16, float* __restrict__ Out) {
    const int bx = blockIdx.x;
    const int J = 31 - (bx >> 4);
    const int b = bx & 15;
    fattn_body<0>(Q, K16, VT16, Out, nullptr, nullptr, b, J, 0, 2 * J + 2, 0);
}

// merge: Out = sum_h(l_h * Ohat_h) / sum_h(l_h); one block per (b, J) tile of 128 rows
__global__ __launch_bounds__(256)
void reduce_kernel(const _Float16* __restrict__ OP, const float* __restrict__ LP,
                   float* __restrict__ Out) {
    const int rb = blockIdx.x;
    const int b  = rb & 15;
    const int J  = rb >> 4;
    const int tid = threadIdx.x;
    const _Float16* p = OP + (size_t)(b * 32 + J) * 4 * 8192;
    const float* l = LP + (size_t)(b * 32 + J) * 4 * 128;
    float* Ob = Out + (size_t)b * S * D + (size_t)J * 8192;
    #pragma unroll
    for (int i = 0; i < 4; ++i) {
        int e8 = tid + 256 * i;                 // half8 group index within 1024
        int q  = e8 >> 3;                       // q-row 0..127
        float lw[4], lsum = 0.f;
        #pragma unroll
        for (int hh = 0; hh < 4; ++hh) { lw[hh] = l[hh * 128 + q]; lsum += lw[hh]; }
        float inv = 1.0f / lsum;
        float acc[8] = {};
        #pragma unroll
        for (int hh = 0; hh < 4; ++hh) {
            half8 v = *(const half8*)(p + (size_t)hh * 8192 + e8 * 8);
            #pragma unroll
            for (int j = 0; j < 8; ++j) acc[j] += lw[hh] * (float)v[j];
        }
        float4 r0, r1;
        r0.x = acc[0]*inv; r0.y = acc[1]*inv; r0.z = acc[2]*inv; r0.w = acc[3]*inv;
        r1.x = acc[4]*inv; r1.y = acc[5]*inv; r1.z = acc[6]*inv; r1.w = acc[7]*inv;
        ((float4*)Ob)[2 * e8]     = r0;
        ((float4*)Ob)[2 * e8 + 1] = r1;
    }
}

extern "C" void kernel_launch(void* const* d_in, const int* in_sizes, int n_in,
                              void* d_out, int out_size, void* d_ws, size_t ws_size,
                              hipStream_t stream) {
    const float* Q = (const float*)d_in[0];
    const float* K = (const float*)d_in[1];
    const float* V = (const float*)d_in[2];
    float* O = (float*)d_out;

    const size_t prepBytes = (size_t)NB * S * D * 2;            // 8.39 MB each
    _Float16* K16  = (_Float16*)d_ws;
    _Float16* VT16 = (_Float16*)((char*)d_ws + prepBytes);

    const size_t opOff = 2 * prepBytes;                         // 16.78 MB
    const size_t opBytes = (size_t)NB * 32 * 4 * 8192 * 2;      // 33.55 MB (f16 partials)
    const size_t lpOff = opOff + opBytes;
    const size_t lpBytes = (size_t)NB * 32 * 4 * 128 * 4;       // 1.05 MB
    const size_t need = lpOff + lpBytes;                        // ~51.4 MB

    hipLaunchKernelGGL(prep_kernel, dim3(S / 64, NB), dim3(256), 0, stream, K, V, K16, VT16);

    if (ws_size >= need) {
        _Float16* OP = (_Float16*)((char*)d_ws + opOff);
        float* LP = (float*)((char*)d_ws + lpOff);
        hipLaunchKernelGGL(fattn_split_kernel, dim3(128 * NB), dim3(256), 0, stream,
                           Q, K16, VT16, OP, LP);
        hipLaunchKernelGGL(reduce_kernel, dim3(32 * NB), dim3(256), 0, stream, OP, LP, O);
    } else {
        hipLaunchKernelGGL(fattn_kernel, dim3(32 * NB), dim3(256), 0, stream, Q, K16, VT16, O);
    }
}